// Round 1
// baseline (577.997 us; speedup 1.0000x reference)
//
#include <hip/hip_runtime.h>
#include <hip/hip_bf16.h>

// Problem constants (B=2, S=1024, D=1024, F=2048, H=16, hd=64, G=4, Epg=2, E=8)
#define TT 2048
#define DD 1024
#define FF 2048
#define SS 1024
#define NHD 16
#define HDD 64
#define NG 4
#define EPG 2
#define NE 8

typedef __attribute__((ext_vector_type(8))) short bf16x8;
typedef __attribute__((ext_vector_type(4))) float f32x4;
typedef __attribute__((ext_vector_type(4))) unsigned short ush4;

__device__ __forceinline__ unsigned short f2bf(float x) {
    unsigned int u = __float_as_uint(x);
    u = (u + 0x7fffu + ((u >> 16) & 1u)) >> 16;
    return (unsigned short)u;
}

__device__ __forceinline__ float wave_sum(float s) {
#pragma unroll
    for (int off = 32; off > 0; off >>= 1) s += __shfl_xor(s, off);
    return s;
}

// ---------------------------------------------------------------------------
// fp32 tiled GEMM:  C[M,N] = A[M,K] * B[N,K]^T + bias[N] (+ resid[M,N])
// 64x64 tile, 256 threads as 16x16, 4x4 micro-tile, BK=16, LDS-transposed tiles.
// ---------------------------------------------------------------------------
__global__ __launch_bounds__(256) void gemm_f32_kernel(
    const float* __restrict__ A, const float* __restrict__ B,
    const float* __restrict__ bias, const float* __restrict__ resid,
    float* __restrict__ C, int M, int N, int K)
{
    __shared__ float As[16][68];
    __shared__ float Bs[16][68];
    const int tx = threadIdx.x & 15, ty = threadIdx.x >> 4;
    const int n0 = blockIdx.x << 6, m0 = blockIdx.y << 6;
    const int sr = threadIdx.x >> 2, sc = (threadIdx.x & 3) << 2;
    float acc[4][4] = {};
    for (int k0 = 0; k0 < K; k0 += 16) {
        float4 av = *(const float4*)(A + (size_t)(m0 + sr) * K + k0 + sc);
        float4 bv = *(const float4*)(B + (size_t)(n0 + sr) * K + k0 + sc);
        As[sc + 0][sr] = av.x; As[sc + 1][sr] = av.y; As[sc + 2][sr] = av.z; As[sc + 3][sr] = av.w;
        Bs[sc + 0][sr] = bv.x; Bs[sc + 1][sr] = bv.y; Bs[sc + 2][sr] = bv.z; Bs[sc + 3][sr] = bv.w;
        __syncthreads();
#pragma unroll
        for (int kk = 0; kk < 16; ++kk) {
            float4 a4 = *(const float4*)&As[kk][ty << 2];
            float4 b4 = *(const float4*)&Bs[kk][tx << 2];
            float aa[4] = {a4.x, a4.y, a4.z, a4.w};
            float bb[4] = {b4.x, b4.y, b4.z, b4.w};
#pragma unroll
            for (int j = 0; j < 4; ++j)
#pragma unroll
                for (int i = 0; i < 4; ++i)
                    acc[j][i] = fmaf(aa[j], bb[i], acc[j][i]);
        }
        __syncthreads();
    }
#pragma unroll
    for (int j = 0; j < 4; ++j) {
        const int m = m0 + (ty << 2) + j;
        const int n = n0 + (tx << 2);
        float4 ov;
        float* po = (float*)&ov;
#pragma unroll
        for (int i = 0; i < 4; ++i) {
            float v = acc[j][i] + bias[n + i];
            if (resid) v += resid[(size_t)m * N + n + i];
            po[i] = v;
        }
        *(float4*)(C + (size_t)m * N + n) = ov;
    }
}

// ---------------------------------------------------------------------------
// fp32 flash attention. grid (S/64, B*H); block 256 as 16x16; per-thread 4q x 4d.
// qkv layout [T][3D]; scale 0.125 folded into Q stage.
// ---------------------------------------------------------------------------
__global__ __launch_bounds__(256) void attn_kernel(const float* __restrict__ qkv,
                                                   float* __restrict__ o)
{
    const int b = blockIdx.y >> 4, h = blockIdx.y & 15;
    const int q0 = blockIdx.x << 6;
    const int tx = threadIdx.x & 15, ty = threadIdx.x >> 4;
    __shared__ float Qt[64][68];  // [d][q]
    __shared__ float KP[64][68];  // K^T [d][kv] during QK; P^T [kv][q] during PV
    __shared__ float Vs[64][68];  // [kv][d]
    const size_t rs3 = 3 * DD;
    const size_t qbase = (size_t)(b * SS + q0) * rs3 + h * HDD;
#pragma unroll
    for (int p = 0; p < 4; ++p) {
        int idx = threadIdx.x + (p << 8);
        int rr = idx >> 4, cc = (idx & 15) << 2;
        float4 v = *(const float4*)(qkv + qbase + (size_t)rr * rs3 + cc);
        Qt[cc + 0][rr] = v.x * 0.125f; Qt[cc + 1][rr] = v.y * 0.125f;
        Qt[cc + 2][rr] = v.z * 0.125f; Qt[cc + 3][rr] = v.w * 0.125f;
    }
    float accO[4][4] = {};
    float m_run[4], l_run[4];
#pragma unroll
    for (int j = 0; j < 4; ++j) { m_run[j] = -3.0e38f; l_run[j] = 0.f; }

    for (int kv0 = 0; kv0 < SS; kv0 += 64) {
        const size_t kbase = (size_t)(b * SS + kv0) * rs3 + DD + h * HDD;
        const size_t vbase = kbase + DD;
#pragma unroll
        for (int p = 0; p < 4; ++p) {
            int idx = threadIdx.x + (p << 8);
            int rr = idx >> 4, cc = (idx & 15) << 2;
            float4 kv4 = *(const float4*)(qkv + kbase + (size_t)rr * rs3 + cc);
            KP[cc + 0][rr] = kv4.x; KP[cc + 1][rr] = kv4.y;
            KP[cc + 2][rr] = kv4.z; KP[cc + 3][rr] = kv4.w;
            float4 vv4 = *(const float4*)(qkv + vbase + (size_t)rr * rs3 + cc);
            *(float4*)&Vs[rr][cc] = vv4;
        }
        __syncthreads();
        float s[4][4] = {};
        for (int kk = 0; kk < 64; ++kk) {
            float4 a4 = *(const float4*)&Qt[kk][ty << 2];
            float4 b4 = *(const float4*)&KP[kk][tx << 2];
            float aa[4] = {a4.x, a4.y, a4.z, a4.w};
            float bb[4] = {b4.x, b4.y, b4.z, b4.w};
#pragma unroll
            for (int j = 0; j < 4; ++j)
#pragma unroll
                for (int i = 0; i < 4; ++i)
                    s[j][i] = fmaf(aa[j], bb[i], s[j][i]);
        }
        __syncthreads();  // everyone done reading K before P overwrites KP
#pragma unroll
        for (int j = 0; j < 4; ++j) {
            float mx = fmaxf(fmaxf(s[j][0], s[j][1]), fmaxf(s[j][2], s[j][3]));
#pragma unroll
            for (int off = 1; off < 16; off <<= 1) mx = fmaxf(mx, __shfl_xor(mx, off));
            float mn = fmaxf(m_run[j], mx);
            float corr = __expf(m_run[j] - mn);
            float ls = 0.f;
#pragma unroll
            for (int i = 0; i < 4; ++i) { s[j][i] = __expf(s[j][i] - mn); ls += s[j][i]; }
#pragma unroll
            for (int off = 1; off < 16; off <<= 1) ls += __shfl_xor(ls, off);
            m_run[j] = mn;
            l_run[j] = l_run[j] * corr + ls;
#pragma unroll
            for (int i = 0; i < 4; ++i) {
                accO[j][i] *= corr;
                KP[(tx << 2) + i][(ty << 2) + j] = s[j][i];  // P^T[kv][q]
            }
        }
        __syncthreads();
        for (int kk = 0; kk < 64; ++kk) {
            float4 p4 = *(const float4*)&KP[kk][ty << 2];
            float4 v4 = *(const float4*)&Vs[kk][tx << 2];
            float aa[4] = {p4.x, p4.y, p4.z, p4.w};
            float bb[4] = {v4.x, v4.y, v4.z, v4.w};
#pragma unroll
            for (int j = 0; j < 4; ++j)
#pragma unroll
                for (int i = 0; i < 4; ++i)
                    accO[j][i] = fmaf(aa[j], bb[i], accO[j][i]);
        }
        __syncthreads();
    }
    const size_t obase = (size_t)(b * SS + q0) * DD + h * HDD;
#pragma unroll
    for (int j = 0; j < 4; ++j) {
        float inv = 1.0f / l_run[j];
        float4 ov = { accO[j][0] * inv, accO[j][1] * inv, accO[j][2] * inv, accO[j][3] * inv };
        *(float4*)(o + obase + (size_t)((ty << 2) + j) * DD + (tx << 2)) = ov;
    }
}

// ---------------------------------------------------------------------------
// LayerNorm per row; writes fp32 (+ optional bf16 copy).
// ---------------------------------------------------------------------------
__global__ __launch_bounds__(256) void ln_kernel(
    const float* __restrict__ in, const float* __restrict__ gamma,
    const float* __restrict__ beta, float* __restrict__ outf,
    unsigned short* __restrict__ outb)
{
    const int t = blockIdx.x;
    const int tid = threadIdx.x;
    __shared__ float red[8];
    const float4 v = ((const float4*)(in + (size_t)t * DD))[tid];
    float s = v.x + v.y + v.z + v.w;
    s = wave_sum(s);
    const int wid = tid >> 6, lane = tid & 63;
    if (lane == 0) red[wid] = s;
    __syncthreads();
    const float mu = (red[0] + red[1] + red[2] + red[3]) * (1.0f / DD);
    const float d0 = v.x - mu, d1 = v.y - mu, d2 = v.z - mu, d3 = v.w - mu;
    float q = d0 * d0 + d1 * d1 + d2 * d2 + d3 * d3;
    q = wave_sum(q);
    if (lane == 0) red[4 + wid] = q;
    __syncthreads();
    const float var = (red[4] + red[5] + red[6] + red[7]) * (1.0f / DD);
    const float rstd = 1.0f / sqrtf(var + 1e-5f);
    const float4 g4 = ((const float4*)gamma)[tid];
    const float4 b4 = ((const float4*)beta)[tid];
    const float o0 = d0 * rstd * g4.x + b4.x;
    const float o1 = d1 * rstd * g4.y + b4.y;
    const float o2 = d2 * rstd * g4.z + b4.z;
    const float o3 = d3 * rstd * g4.w + b4.w;
    float4 ov = {o0, o1, o2, o3};
    ((float4*)(outf + (size_t)t * DD))[tid] = ov;
    if (outb) {
        ush4 w = { f2bf(o0), f2bf(o1), f2bf(o2), f2bf(o3) };
        *(ush4*)(outb + (size_t)t * DD + (tid << 2)) = w;
    }
}

// ---------------------------------------------------------------------------
// Hierarchical top-1 routing. One wave per token (fp32, exact-order reductions).
// ---------------------------------------------------------------------------
__global__ __launch_bounds__(256) void route_kernel(
    const float* __restrict__ x1, const float* __restrict__ wg,
    const float* __restrict__ bg, const float* __restrict__ we,
    const float* __restrict__ be, int* __restrict__ eid,
    float* __restrict__ gate, int* __restrict__ counts)
{
    const int lane = threadIdx.x & 63;
    const int t = (blockIdx.x << 2) + (threadIdx.x >> 6);
    const float* row = x1 + (size_t)t * DD;
    float zg[NG] = {};
    float ze[NG][EPG] = {};
#pragma unroll
    for (int jj = 0; jj < 16; ++jj) {
        const int c = (lane << 4) + jj;
        const float xv = row[c];
#pragma unroll
        for (int g = 0; g < NG; ++g) {
            zg[g] = fmaf(xv, wg[c * NG + g], zg[g]);
#pragma unroll
            for (int e2 = 0; e2 < EPG; ++e2)
                ze[g][e2] = fmaf(xv, we[(g * DD + c) * EPG + e2], ze[g][e2]);
        }
    }
#pragma unroll
    for (int off = 1; off < 64; off <<= 1) {
#pragma unroll
        for (int g = 0; g < NG; ++g) {
            zg[g] += __shfl_xor(zg[g], off);
#pragma unroll
            for (int e2 = 0; e2 < EPG; ++e2) ze[g][e2] += __shfl_xor(ze[g][e2], off);
        }
    }
    if (lane == 0) {
        float z[NG];
#pragma unroll
        for (int g = 0; g < NG; ++g) z[g] = zg[g] + bg[g];
        int gi = 0; float zb = z[0];
#pragma unroll
        for (int g = 1; g < NG; ++g) if (z[g] > zb) { zb = z[g]; gi = g; }
        float se = 0.f;
#pragma unroll
        for (int g = 0; g < NG; ++g) se += __expf(z[g] - zb);
        const float gprob = 1.0f / se;
        float e0 = 0.f, e1 = 0.f;
#pragma unroll
        for (int g = 0; g < NG; ++g) {
            if (g == gi) { e0 = ze[g][0] + be[g * EPG + 0]; e1 = ze[g][1] + be[g * EPG + 1]; }
        }
        const int ei = (e1 > e0) ? 1 : 0;
        const float ehi = ei ? e1 : e0, elo = ei ? e0 : e1;
        const float eprob = 1.0f / (1.0f + __expf(elo - ehi));
        eid[t] = gi * EPG + ei;
        gate[t] = gprob * eprob;
        atomicAdd(&counts[gi * EPG + ei], 1);
    }
}

__global__ void zero_counts_kernel(int* __restrict__ counts) {
    if (threadIdx.x < NE) counts[threadIdx.x] = 0;
}

__global__ void offsets_kernel(const int* __restrict__ counts, int* __restrict__ offs,
                               int* __restrict__ cursor) {
    if (threadIdx.x == 0) {
        int run = 0;
        for (int e = 0; e < NE; ++e) { offs[e] = run; cursor[e] = run; run += counts[e]; }
        offs[NE] = run;
    }
}

__global__ __launch_bounds__(256) void scatter_kernel(const int* __restrict__ eid,
                                                      int* __restrict__ cursor,
                                                      int* __restrict__ perm) {
    const int t = blockIdx.x * 256 + threadIdx.x;
    const int slot = atomicAdd(&cursor[eid[t]], 1);
    perm[slot] = t;
}

// ---------------------------------------------------------------------------
// fp32 [batch][R][C] -> bf16 [batch][C][R] (LDS-tiled transpose + convert)
// ---------------------------------------------------------------------------
__global__ __launch_bounds__(256) void transpose_bf16_kernel(
    const float* __restrict__ in, unsigned short* __restrict__ out, int R, int C)
{
    __shared__ float tile[32][33];
    const int c0 = blockIdx.x << 5, r0 = blockIdx.y << 5;
    const size_t bo = (size_t)blockIdx.z * R * C;
    const int tc = threadIdx.x & 31, tr8 = threadIdx.x >> 5;
#pragma unroll
    for (int p = 0; p < 4; ++p) {
        const int rr = tr8 + (p << 3);
        tile[rr][tc] = in[bo + (size_t)(r0 + rr) * C + c0 + tc];
    }
    __syncthreads();
#pragma unroll
    for (int p = 0; p < 4; ++p) {
        const int rr = tr8 + (p << 3);
        out[bo + (size_t)(c0 + rr) * R + r0 + tc] = f2bf(tile[tc][rr]);
    }
}

// ---------------------------------------------------------------------------
// MoE expert GEMM 1: h[slot][F] = relu(x1b[perm[slot]] . w1t[e]^T + b1[e])
// bf16 MFMA 16x16x32; 64x64 tile, BK=64, 4 waves (each 16 rows x 64 cols).
// grid (F/64, 8*32 tile slots).
// ---------------------------------------------------------------------------
__global__ __launch_bounds__(256) void moe_gemm1_kernel(
    const unsigned short* __restrict__ x1b, const unsigned short* __restrict__ w1t,
    const float* __restrict__ b1, const int* __restrict__ offs,
    const int* __restrict__ perm, unsigned short* __restrict__ hbuf)
{
    const int e = blockIdx.y >> 5, mt = blockIdx.y & 31;
    const int row0 = offs[e] + (mt << 6);
    const int rend = offs[e + 1];
    if (row0 >= rend) return;
    const int valid = (rend - row0 < 64) ? (rend - row0) : 64;
    const int n0 = blockIdx.x << 6;
    __shared__ unsigned short As[64][72];
    __shared__ unsigned short Bs[64][72];
    const int lane = threadIdx.x & 63, wid = threadIdx.x >> 6;
    const int l15 = lane & 15, lg = lane >> 4;
    f32x4 acc0 = {0.f, 0.f, 0.f, 0.f}, acc1 = acc0, acc2 = acc0, acc3 = acc0;
    const unsigned short* Bbase = w1t + (size_t)e * FF * DD + (size_t)n0 * DD;
    for (int k0 = 0; k0 < DD; k0 += 64) {
#pragma unroll
        for (int rep = 0; rep < 2; ++rep) {
            const int idx = threadIdx.x + (rep << 8);
            const int rr = idx >> 3, c8 = (idx & 7) << 3;
            bf16x8 av = {0, 0, 0, 0, 0, 0, 0, 0};
            if (rr < valid) {
                const int tk = perm[row0 + rr];
                av = *(const bf16x8*)(x1b + (size_t)tk * DD + k0 + c8);
            }
            *(bf16x8*)&As[rr][c8] = av;
            const bf16x8 bv = *(const bf16x8*)(Bbase + (size_t)rr * DD + k0 + c8);
            *(bf16x8*)&Bs[rr][c8] = bv;
        }
        __syncthreads();
#pragma unroll
        for (int ks = 0; ks < 2; ++ks) {
            const int kc = (ks << 5) + (lg << 3);
            const bf16x8 a  = *(const bf16x8*)&As[(wid << 4) + l15][kc];
            const bf16x8 f0 = *(const bf16x8*)&Bs[ 0 + l15][kc];
            const bf16x8 f1 = *(const bf16x8*)&Bs[16 + l15][kc];
            const bf16x8 f2 = *(const bf16x8*)&Bs[32 + l15][kc];
            const bf16x8 f3 = *(const bf16x8*)&Bs[48 + l15][kc];
            acc0 = __builtin_amdgcn_mfma_f32_16x16x32_bf16(a, f0, acc0, 0, 0, 0);
            acc1 = __builtin_amdgcn_mfma_f32_16x16x32_bf16(a, f1, acc1, 0, 0, 0);
            acc2 = __builtin_amdgcn_mfma_f32_16x16x32_bf16(a, f2, acc2, 0, 0, 0);
            acc3 = __builtin_amdgcn_mfma_f32_16x16x32_bf16(a, f3, acc3, 0, 0, 0);
        }
        __syncthreads();
    }
    const float* bias = b1 + e * FF + n0;
    const int mbase = (wid << 4) + (lg << 2);
#pragma unroll
    for (int nt = 0; nt < 4; ++nt) {
        const f32x4 ac = (nt == 0) ? acc0 : (nt == 1) ? acc1 : (nt == 2) ? acc2 : acc3;
        const int n = (nt << 4) + l15;
#pragma unroll
        for (int r2 = 0; r2 < 4; ++r2) {
            const int m = mbase + r2;
            if (m < valid) {
                float v = ac[r2] + bias[n];
                v = fmaxf(v, 0.f);
                hbuf[(size_t)(row0 + m) * FF + n0 + n] = f2bf(v);
            }
        }
    }
}

// ---------------------------------------------------------------------------
// MoE expert GEMM 2: res2[tk] = x1[tk] + gate[tk]*(h[slot] . w2t[e]^T + b2[e])
// grid (D/64, 8*32).
// ---------------------------------------------------------------------------
__global__ __launch_bounds__(256) void moe_gemm2_kernel(
    const unsigned short* __restrict__ hbuf, const unsigned short* __restrict__ w2t,
    const float* __restrict__ b2, const int* __restrict__ offs,
    const int* __restrict__ perm, const float* __restrict__ gate,
    const float* __restrict__ x1, float* __restrict__ res2)
{
    const int e = blockIdx.y >> 5, mt = blockIdx.y & 31;
    const int row0 = offs[e] + (mt << 6);
    const int rend = offs[e + 1];
    if (row0 >= rend) return;
    const int valid = (rend - row0 < 64) ? (rend - row0) : 64;
    const int n0 = blockIdx.x << 6;
    __shared__ unsigned short As[64][72];
    __shared__ unsigned short Bs[64][72];
    const int lane = threadIdx.x & 63, wid = threadIdx.x >> 6;
    const int l15 = lane & 15, lg = lane >> 4;
    f32x4 acc0 = {0.f, 0.f, 0.f, 0.f}, acc1 = acc0, acc2 = acc0, acc3 = acc0;
    const unsigned short* Bbase = w2t + (size_t)e * DD * FF + (size_t)n0 * FF;
    for (int k0 = 0; k0 < FF; k0 += 64) {
#pragma unroll
        for (int rep = 0; rep < 2; ++rep) {
            const int idx = threadIdx.x + (rep << 8);
            const int rr = idx >> 3, c8 = (idx & 7) << 3;
            bf16x8 av = {0, 0, 0, 0, 0, 0, 0, 0};
            if (rr < valid) av = *(const bf16x8*)(hbuf + (size_t)(row0 + rr) * FF + k0 + c8);
            *(bf16x8*)&As[rr][c8] = av;
            const bf16x8 bv = *(const bf16x8*)(Bbase + (size_t)rr * FF + k0 + c8);
            *(bf16x8*)&Bs[rr][c8] = bv;
        }
        __syncthreads();
#pragma unroll
        for (int ks = 0; ks < 2; ++ks) {
            const int kc = (ks << 5) + (lg << 3);
            const bf16x8 a  = *(const bf16x8*)&As[(wid << 4) + l15][kc];
            const bf16x8 f0 = *(const bf16x8*)&Bs[ 0 + l15][kc];
            const bf16x8 f1 = *(const bf16x8*)&Bs[16 + l15][kc];
            const bf16x8 f2 = *(const bf16x8*)&Bs[32 + l15][kc];
            const bf16x8 f3 = *(const bf16x8*)&Bs[48 + l15][kc];
            acc0 = __builtin_amdgcn_mfma_f32_16x16x32_bf16(a, f0, acc0, 0, 0, 0);
            acc1 = __builtin_amdgcn_mfma_f32_16x16x32_bf16(a, f1, acc1, 0, 0, 0);
            acc2 = __builtin_amdgcn_mfma_f32_16x16x32_bf16(a, f2, acc2, 0, 0, 0);
            acc3 = __builtin_amdgcn_mfma_f32_16x16x32_bf16(a, f3, acc3, 0, 0, 0);
        }
        __syncthreads();
    }
    const int mbase = (wid << 4) + (lg << 2);
#pragma unroll
    for (int nt = 0; nt < 4; ++nt) {
        const f32x4 ac = (nt == 0) ? acc0 : (nt == 1) ? acc1 : (nt == 2) ? acc2 : acc3;
        const int nl = (nt << 4) + l15;
#pragma unroll
        for (int r2 = 0; r2 < 4; ++r2) {
            const int m = mbase + r2;
            if (m < valid) {
                const int tk = perm[row0 + m];
                const float v = ac[r2] + b2[e * DD + n0 + nl];
                const size_t oi = (size_t)tk * DD + n0 + nl;
                res2[oi] = x1[oi] + gate[tk] * v;
            }
        }
    }
}

// ---------------------------------------------------------------------------
extern "C" void kernel_launch(void* const* d_in, const int* in_sizes, int n_in,
                              void* d_out, int out_size, void* d_ws, size_t ws_size,
                              hipStream_t stream)
{
    (void)in_sizes; (void)n_in; (void)out_size; (void)ws_size;
    const float* x   = (const float*)d_in[0];
    const float* wi  = (const float*)d_in[1];
    const float* bi  = (const float*)d_in[2];
    const float* wo  = (const float*)d_in[3];
    const float* bo  = (const float*)d_in[4];
    const float* g1  = (const float*)d_in[5];
    const float* be1 = (const float*)d_in[6];
    const float* g2  = (const float*)d_in[7];
    const float* be2 = (const float*)d_in[8];
    const float* wgr = (const float*)d_in[9];
    const float* bgr = (const float*)d_in[10];
    const float* wex = (const float*)d_in[11];
    const float* bex = (const float*)d_in[12];
    const float* w1  = (const float*)d_in[13];
    const float* b1  = (const float*)d_in[14];
    const float* w2  = (const float*)d_in[15];
    const float* b2  = (const float*)d_in[16];
    float* out = (float*)d_out;

    char* ws = (char*)d_ws;
    float* qkv            = (float*)(ws + 0);          // 25,165,824 B (reused below)
    unsigned short* hbuf  = (unsigned short*)(ws + 0); // 8,388,608 B (aliases qkv)
    float* res2           = (float*)(ws + 8388608);    // 8,388,608 B (aliases qkv)
    float* obuf           = (float*)(ws + 25165824);
    float* res1           = (float*)(ws + 33554432);
    float* x1             = (float*)(ws + 41943040);
    unsigned short* x1b   = (unsigned short*)(ws + 50331648);
    unsigned short* w1t   = (unsigned short*)(ws + 54525952);
    unsigned short* w2t   = (unsigned short*)(ws + 88080384);
    char* misc = ws + 121634816;
    int*   eid    = (int*)(misc);
    float* gate   = (float*)(misc + 8192);
    int*   perm   = (int*)(misc + 16384);
    int*   counts = (int*)(misc + 24576);
    int*   offs   = (int*)(misc + 24640);
    int*   cursor = (int*)(misc + 24704);

    // Expert weights -> bf16 [N][K] layouts (for coalesced MFMA B-tiles)
    transpose_bf16_kernel<<<dim3(FF / 32, DD / 32, NE), dim3(256), 0, stream>>>(w1, w1t, DD, FF);
    transpose_bf16_kernel<<<dim3(DD / 32, FF / 32, NE), dim3(256), 0, stream>>>(w2, w2t, FF, DD);

    // qkv = x @ in_proj_w^T + b   (fp32, routing-critical path)
    gemm_f32_kernel<<<dim3(3 * DD / 64, TT / 64), dim3(256), 0, stream>>>(
        x, wi, bi, (const float*)nullptr, qkv, TT, 3 * DD, DD);

    // attention (fp32 flash)
    attn_kernel<<<dim3(SS / 64, 2 * NHD), dim3(256), 0, stream>>>(qkv, obuf);

    // out-proj + residual: res1 = x + o @ wo^T + bo
    gemm_f32_kernel<<<dim3(DD / 64, TT / 64), dim3(256), 0, stream>>>(
        obuf, wo, bo, x, res1, TT, DD, DD);

    // LN1 -> x1 (fp32) + x1b (bf16)
    ln_kernel<<<dim3(TT), dim3(256), 0, stream>>>(res1, g1, be1, x1, x1b);

    // routing
    zero_counts_kernel<<<dim3(1), dim3(64), 0, stream>>>(counts);
    route_kernel<<<dim3(TT / 4), dim3(256), 0, stream>>>(x1, wgr, bgr, wex, bex, eid, gate, counts);
    offsets_kernel<<<dim3(1), dim3(64), 0, stream>>>(counts, offs, cursor);
    scatter_kernel<<<dim3(TT / 256), dim3(256), 0, stream>>>(eid, cursor, perm);

    // sparse expert FFN (bf16 MFMA)
    moe_gemm1_kernel<<<dim3(FF / 64, NE * 32), dim3(256), 0, stream>>>(x1b, w1t, b1, offs, perm, hbuf);
    moe_gemm2_kernel<<<dim3(DD / 64, NE * 32), dim3(256), 0, stream>>>(hbuf, w2t, b2, offs, perm, gate, x1, res2);

    // LN2 -> final output (fp32)
    ln_kernel<<<dim3(TT), dim3(256), 0, stream>>>(res2, g2, be2, out, (unsigned short*)nullptr);
}

// Round 2
// 440.322 us; speedup vs baseline: 1.3127x; 1.3127x over previous
//
#include <hip/hip_runtime.h>
#include <hip/hip_bf16.h>

// Problem constants (B=2, S=1024, D=1024, F=2048, H=16, hd=64, G=4, Epg=2, E=8)
#define TT 2048
#define DD 1024
#define FF 2048
#define SS 1024
#define NHD 16
#define HDD 64
#define NG 4
#define EPG 2
#define NE 8

typedef __attribute__((ext_vector_type(8))) short bf16x8;
typedef __attribute__((ext_vector_type(4))) float f32x4;
typedef __attribute__((ext_vector_type(4))) unsigned short ush4;

__device__ __forceinline__ unsigned short f2bf(float x) {
    unsigned int u = __float_as_uint(x);
    u = (u + 0x7fffu + ((u >> 16) & 1u)) >> 16;
    return (unsigned short)u;
}

__device__ __forceinline__ float wave_sum(float s) {
#pragma unroll
    for (int off = 32; off > 0; off >>= 1) s += __shfl_xor(s, off);
    return s;
}

// ---------------------------------------------------------------------------
// fp32 -> bf16 hi/lo split planes (Sterbenz: lo residual exact in fp32)
// ---------------------------------------------------------------------------
__global__ __launch_bounds__(256) void split_bf16_kernel(
    const float* __restrict__ in, unsigned short* __restrict__ hi,
    unsigned short* __restrict__ lo, int n4)
{
    const int i = blockIdx.x * 256 + threadIdx.x;
    if (i >= n4) return;
    const float4 v = ((const float4*)in)[i];
    float vv[4] = {v.x, v.y, v.z, v.w};
    ush4 h, l;
#pragma unroll
    for (int j = 0; j < 4; ++j) {
        const unsigned short hb = f2bf(vv[j]);
        const float hf = __uint_as_float((unsigned int)hb << 16);
        ((unsigned short*)&h)[j] = hb;
        ((unsigned short*)&l)[j] = f2bf(vv[j] - hf);
    }
    ((ush4*)hi)[i] = h;
    ((ush4*)lo)[i] = l;
}

// ---------------------------------------------------------------------------
// Split-precision GEMM: C[M,N] = A[M,K] . B[N,K]^T + bias (+resid), where
// A ~ Ah+Al, B ~ Bh+Bl (bf16 planes). 3-term MFMA: AhBh + AhBl + AlBh.
// 128x128 tile, BK=64, 4 waves (2x2 of 64x64), XOR-swizzled LDS.
// ---------------------------------------------------------------------------
__global__ __launch_bounds__(256, 2) void gemm_split_kernel(
    const unsigned short* __restrict__ Ah, const unsigned short* __restrict__ Al,
    const unsigned short* __restrict__ Bh, const unsigned short* __restrict__ Bl,
    const float* __restrict__ bias, const float* __restrict__ resid,
    float* __restrict__ C, int M, int N, int K)
{
    __shared__ unsigned short sAh[128 * 64];
    __shared__ unsigned short sAl[128 * 64];
    __shared__ unsigned short sBh[128 * 64];
    __shared__ unsigned short sBl[128 * 64];
    const int tid = threadIdx.x;
    const int lane = tid & 63, wid = tid >> 6;
    const int l15 = lane & 15, lg = lane >> 4;
    const int wr = wid >> 1, wc = wid & 1;
    const int n0 = blockIdx.x << 7, m0 = blockIdx.y << 7;

    f32x4 acc[4][4];
#pragma unroll
    for (int mi = 0; mi < 4; ++mi)
#pragma unroll
        for (int ni = 0; ni < 4; ++ni) acc[mi][ni] = (f32x4){0.f, 0.f, 0.f, 0.f};

    for (int k0 = 0; k0 < K; k0 += 64) {
#pragma unroll
        for (int r = 0; r < 4; ++r) {
            const int s = tid + (r << 8);           // 16B slot idx, [128 rows][8 slots]
            const int row = s >> 3, c = s & 7;
            const int phys = (s & ~7) | (c ^ (row & 7));
            const size_t ga = (size_t)(m0 + row) * K + k0 + (c << 3);
            const size_t gb = (size_t)(n0 + row) * K + k0 + (c << 3);
            *(bf16x8*)&sAh[phys << 3] = *(const bf16x8*)(Ah + ga);
            *(bf16x8*)&sAl[phys << 3] = *(const bf16x8*)(Al + ga);
            *(bf16x8*)&sBh[phys << 3] = *(const bf16x8*)(Bh + gb);
            *(bf16x8*)&sBl[phys << 3] = *(const bf16x8*)(Bl + gb);
        }
        __syncthreads();
#pragma unroll
        for (int ks = 0; ks < 2; ++ks) {
            bf16x8 ah[4], al[4], bh[4], bl[4];
            const int ac = (ks << 2) + lg;          // 8-elem k-chunk within the 64
#pragma unroll
            for (int i = 0; i < 4; ++i) {
                const int ar = (wr << 6) + (i << 4) + l15;
                const int pa = ((ar << 3) | (ac ^ (ar & 7))) << 3;
                ah[i] = *(const bf16x8*)&sAh[pa];
                al[i] = *(const bf16x8*)&sAl[pa];
                const int br = (wc << 6) + (i << 4) + l15;
                const int pb = ((br << 3) | (ac ^ (br & 7))) << 3;
                bh[i] = *(const bf16x8*)&sBh[pb];
                bl[i] = *(const bf16x8*)&sBl[pb];
            }
#pragma unroll
            for (int mi = 0; mi < 4; ++mi)
#pragma unroll
                for (int ni = 0; ni < 4; ++ni) {
                    acc[mi][ni] = __builtin_amdgcn_mfma_f32_16x16x32_bf16(ah[mi], bh[ni], acc[mi][ni], 0, 0, 0);
                    acc[mi][ni] = __builtin_amdgcn_mfma_f32_16x16x32_bf16(ah[mi], bl[ni], acc[mi][ni], 0, 0, 0);
                    acc[mi][ni] = __builtin_amdgcn_mfma_f32_16x16x32_bf16(al[mi], bh[ni], acc[mi][ni], 0, 0, 0);
                }
        }
        __syncthreads();
    }
#pragma unroll
    for (int mi = 0; mi < 4; ++mi)
#pragma unroll
        for (int ni = 0; ni < 4; ++ni)
#pragma unroll
            for (int r2 = 0; r2 < 4; ++r2) {
                const int m = m0 + (wr << 6) + (mi << 4) + (lg << 2) + r2;
                const int n = n0 + (wc << 6) + (ni << 4) + l15;
                float v = acc[mi][ni][r2] + bias[n];
                if (resid) v += resid[(size_t)m * N + n];
                C[(size_t)m * N + n] = v;
            }
}

// ---------------------------------------------------------------------------
// fp32 flash attention. grid (S/64, B*H); block 256 as 16x16; per-thread 4q x 4d.
// ---------------------------------------------------------------------------
__global__ __launch_bounds__(256) void attn_kernel(const float* __restrict__ qkv,
                                                   float* __restrict__ o)
{
    const int b = blockIdx.y >> 4, h = blockIdx.y & 15;
    const int q0 = blockIdx.x << 6;
    const int tx = threadIdx.x & 15, ty = threadIdx.x >> 4;
    __shared__ float Qt[64][68];  // [d][q]
    __shared__ float KP[64][68];  // K^T [d][kv] during QK; P^T [kv][q] during PV
    __shared__ float Vs[64][68];  // [kv][d]
    const size_t rs3 = 3 * DD;
    const size_t qbase = (size_t)(b * SS + q0) * rs3 + h * HDD;
#pragma unroll
    for (int p = 0; p < 4; ++p) {
        int idx = threadIdx.x + (p << 8);
        int rr = idx >> 4, cc = (idx & 15) << 2;
        float4 v = *(const float4*)(qkv + qbase + (size_t)rr * rs3 + cc);
        Qt[cc + 0][rr] = v.x * 0.125f; Qt[cc + 1][rr] = v.y * 0.125f;
        Qt[cc + 2][rr] = v.z * 0.125f; Qt[cc + 3][rr] = v.w * 0.125f;
    }
    float accO[4][4] = {};
    float m_run[4], l_run[4];
#pragma unroll
    for (int j = 0; j < 4; ++j) { m_run[j] = -3.0e38f; l_run[j] = 0.f; }

    for (int kv0 = 0; kv0 < SS; kv0 += 64) {
        const size_t kbase = (size_t)(b * SS + kv0) * rs3 + DD + h * HDD;
        const size_t vbase = kbase + DD;
#pragma unroll
        for (int p = 0; p < 4; ++p) {
            int idx = threadIdx.x + (p << 8);
            int rr = idx >> 4, cc = (idx & 15) << 2;
            float4 kv4 = *(const float4*)(qkv + kbase + (size_t)rr * rs3 + cc);
            KP[cc + 0][rr] = kv4.x; KP[cc + 1][rr] = kv4.y;
            KP[cc + 2][rr] = kv4.z; KP[cc + 3][rr] = kv4.w;
            float4 vv4 = *(const float4*)(qkv + vbase + (size_t)rr * rs3 + cc);
            *(float4*)&Vs[rr][cc] = vv4;
        }
        __syncthreads();
        float s[4][4] = {};
        for (int kk = 0; kk < 64; ++kk) {
            float4 a4 = *(const float4*)&Qt[kk][ty << 2];
            float4 b4 = *(const float4*)&KP[kk][tx << 2];
            float aa[4] = {a4.x, a4.y, a4.z, a4.w};
            float bb[4] = {b4.x, b4.y, b4.z, b4.w};
#pragma unroll
            for (int j = 0; j < 4; ++j)
#pragma unroll
                for (int i = 0; i < 4; ++i)
                    s[j][i] = fmaf(aa[j], bb[i], s[j][i]);
        }
        __syncthreads();  // everyone done reading K before P overwrites KP
#pragma unroll
        for (int j = 0; j < 4; ++j) {
            float mx = fmaxf(fmaxf(s[j][0], s[j][1]), fmaxf(s[j][2], s[j][3]));
#pragma unroll
            for (int off = 1; off < 16; off <<= 1) mx = fmaxf(mx, __shfl_xor(mx, off));
            float mn = fmaxf(m_run[j], mx);
            float corr = __expf(m_run[j] - mn);
            float ls = 0.f;
#pragma unroll
            for (int i = 0; i < 4; ++i) { s[j][i] = __expf(s[j][i] - mn); ls += s[j][i]; }
#pragma unroll
            for (int off = 1; off < 16; off <<= 1) ls += __shfl_xor(ls, off);
            m_run[j] = mn;
            l_run[j] = l_run[j] * corr + ls;
#pragma unroll
            for (int i = 0; i < 4; ++i) {
                accO[j][i] *= corr;
                KP[(tx << 2) + i][(ty << 2) + j] = s[j][i];  // P^T[kv][q]
            }
        }
        __syncthreads();
        for (int kk = 0; kk < 64; ++kk) {
            float4 p4 = *(const float4*)&KP[kk][ty << 2];
            float4 v4 = *(const float4*)&Vs[kk][tx << 2];
            float aa[4] = {p4.x, p4.y, p4.z, p4.w};
            float bb[4] = {v4.x, v4.y, v4.z, v4.w};
#pragma unroll
            for (int j = 0; j < 4; ++j)
#pragma unroll
                for (int i = 0; i < 4; ++i)
                    accO[j][i] = fmaf(aa[j], bb[i], accO[j][i]);
        }
        __syncthreads();
    }
    const size_t obase = (size_t)(b * SS + q0) * DD + h * HDD;
#pragma unroll
    for (int j = 0; j < 4; ++j) {
        float inv = 1.0f / l_run[j];
        float4 ov = { accO[j][0] * inv, accO[j][1] * inv, accO[j][2] * inv, accO[j][3] * inv };
        *(float4*)(o + obase + (size_t)((ty << 2) + j) * DD + (tx << 2)) = ov;
    }
}

// ---------------------------------------------------------------------------
// LayerNorm per row; writes fp32 (+ optional bf16 copy).
// ---------------------------------------------------------------------------
__global__ __launch_bounds__(256) void ln_kernel(
    const float* __restrict__ in, const float* __restrict__ gamma,
    const float* __restrict__ beta, float* __restrict__ outf,
    unsigned short* __restrict__ outb)
{
    const int t = blockIdx.x;
    const int tid = threadIdx.x;
    __shared__ float red[8];
    const float4 v = ((const float4*)(in + (size_t)t * DD))[tid];
    float s = v.x + v.y + v.z + v.w;
    s = wave_sum(s);
    const int wid = tid >> 6, lane = tid & 63;
    if (lane == 0) red[wid] = s;
    __syncthreads();
    const float mu = (red[0] + red[1] + red[2] + red[3]) * (1.0f / DD);
    const float d0 = v.x - mu, d1 = v.y - mu, d2 = v.z - mu, d3 = v.w - mu;
    float q = d0 * d0 + d1 * d1 + d2 * d2 + d3 * d3;
    q = wave_sum(q);
    if (lane == 0) red[4 + wid] = q;
    __syncthreads();
    const float var = (red[4] + red[5] + red[6] + red[7]) * (1.0f / DD);
    const float rstd = 1.0f / sqrtf(var + 1e-5f);
    const float4 g4 = ((const float4*)gamma)[tid];
    const float4 b4 = ((const float4*)beta)[tid];
    const float o0 = d0 * rstd * g4.x + b4.x;
    const float o1 = d1 * rstd * g4.y + b4.y;
    const float o2 = d2 * rstd * g4.z + b4.z;
    const float o3 = d3 * rstd * g4.w + b4.w;
    float4 ov = {o0, o1, o2, o3};
    ((float4*)(outf + (size_t)t * DD))[tid] = ov;
    if (outb) {
        ush4 w = { f2bf(o0), f2bf(o1), f2bf(o2), f2bf(o3) };
        *(ush4*)(outb + (size_t)t * DD + (tid << 2)) = w;
    }
}

// ---------------------------------------------------------------------------
// Hierarchical top-1 routing. One wave per token (fp32, exact-order reductions).
// ---------------------------------------------------------------------------
__global__ __launch_bounds__(256) void route_kernel(
    const float* __restrict__ x1, const float* __restrict__ wg,
    const float* __restrict__ bg, const float* __restrict__ we,
    const float* __restrict__ be, int* __restrict__ eid,
    float* __restrict__ gate, int* __restrict__ counts)
{
    const int lane = threadIdx.x & 63;
    const int t = (blockIdx.x << 2) + (threadIdx.x >> 6);
    const float* row = x1 + (size_t)t * DD;
    float zg[NG] = {};
    float ze[NG][EPG] = {};
#pragma unroll
    for (int jj = 0; jj < 16; ++jj) {
        const int c = (lane << 4) + jj;
        const float xv = row[c];
#pragma unroll
        for (int g = 0; g < NG; ++g) {
            zg[g] = fmaf(xv, wg[c * NG + g], zg[g]);
#pragma unroll
            for (int e2 = 0; e2 < EPG; ++e2)
                ze[g][e2] = fmaf(xv, we[(g * DD + c) * EPG + e2], ze[g][e2]);
        }
    }
#pragma unroll
    for (int off = 1; off < 64; off <<= 1) {
#pragma unroll
        for (int g = 0; g < NG; ++g) {
            zg[g] += __shfl_xor(zg[g], off);
#pragma unroll
            for (int e2 = 0; e2 < EPG; ++e2) ze[g][e2] += __shfl_xor(ze[g][e2], off);
        }
    }
    if (lane == 0) {
        float z[NG];
#pragma unroll
        for (int g = 0; g < NG; ++g) z[g] = zg[g] + bg[g];
        int gi = 0; float zb = z[0];
#pragma unroll
        for (int g = 1; g < NG; ++g) if (z[g] > zb) { zb = z[g]; gi = g; }
        float se = 0.f;
#pragma unroll
        for (int g = 0; g < NG; ++g) se += __expf(z[g] - zb);
        const float gprob = 1.0f / se;
        float e0 = 0.f, e1 = 0.f;
#pragma unroll
        for (int g = 0; g < NG; ++g) {
            if (g == gi) { e0 = ze[g][0] + be[g * EPG + 0]; e1 = ze[g][1] + be[g * EPG + 1]; }
        }
        const int ei = (e1 > e0) ? 1 : 0;
        const float ehi = ei ? e1 : e0, elo = ei ? e0 : e1;
        const float eprob = 1.0f / (1.0f + __expf(elo - ehi));
        eid[t] = gi * EPG + ei;
        gate[t] = gprob * eprob;
        atomicAdd(&counts[gi * EPG + ei], 1);
    }
}

__global__ void zero_counts_kernel(int* __restrict__ counts) {
    if (threadIdx.x < NE) counts[threadIdx.x] = 0;
}

__global__ void offsets_kernel(const int* __restrict__ counts, int* __restrict__ offs,
                               int* __restrict__ cursor) {
    if (threadIdx.x == 0) {
        int run = 0;
        for (int e = 0; e < NE; ++e) { offs[e] = run; cursor[e] = run; run += counts[e]; }
        offs[NE] = run;
    }
}

__global__ __launch_bounds__(256) void scatter_kernel(const int* __restrict__ eid,
                                                      int* __restrict__ cursor,
                                                      int* __restrict__ perm) {
    const int t = blockIdx.x * 256 + threadIdx.x;
    const int slot = atomicAdd(&cursor[eid[t]], 1);
    perm[slot] = t;
}

// ---------------------------------------------------------------------------
// fp32 [batch][R][C] -> bf16 [batch][C][R] (LDS-tiled transpose + convert)
// ---------------------------------------------------------------------------
__global__ __launch_bounds__(256) void transpose_bf16_kernel(
    const float* __restrict__ in, unsigned short* __restrict__ out, int R, int C)
{
    __shared__ float tile[32][33];
    const int c0 = blockIdx.x << 5, r0 = blockIdx.y << 5;
    const size_t bo = (size_t)blockIdx.z * R * C;
    const int tc = threadIdx.x & 31, tr8 = threadIdx.x >> 5;
#pragma unroll
    for (int p = 0; p < 4; ++p) {
        const int rr = tr8 + (p << 3);
        tile[rr][tc] = in[bo + (size_t)(r0 + rr) * C + c0 + tc];
    }
    __syncthreads();
#pragma unroll
    for (int p = 0; p < 4; ++p) {
        const int rr = tr8 + (p << 3);
        out[bo + (size_t)(c0 + rr) * R + r0 + tc] = f2bf(tile[tc][rr]);
    }
}

// ---------------------------------------------------------------------------
// MoE expert GEMM 1: h[slot][F] = relu(x1b[perm[slot]] . w1t[e]^T + b1[e])
// ---------------------------------------------------------------------------
__global__ __launch_bounds__(256) void moe_gemm1_kernel(
    const unsigned short* __restrict__ x1b, const unsigned short* __restrict__ w1t,
    const float* __restrict__ b1, const int* __restrict__ offs,
    const int* __restrict__ perm, unsigned short* __restrict__ hbuf)
{
    const int e = blockIdx.y >> 5, mt = blockIdx.y & 31;
    const int row0 = offs[e] + (mt << 6);
    const int rend = offs[e + 1];
    if (row0 >= rend) return;
    const int valid = (rend - row0 < 64) ? (rend - row0) : 64;
    const int n0 = blockIdx.x << 6;
    __shared__ unsigned short As[64][72];
    __shared__ unsigned short Bs[64][72];
    const int lane = threadIdx.x & 63, wid = threadIdx.x >> 6;
    const int l15 = lane & 15, lg = lane >> 4;
    f32x4 acc0 = {0.f, 0.f, 0.f, 0.f}, acc1 = acc0, acc2 = acc0, acc3 = acc0;
    const unsigned short* Bbase = w1t + (size_t)e * FF * DD + (size_t)n0 * DD;
    for (int k0 = 0; k0 < DD; k0 += 64) {
#pragma unroll
        for (int rep = 0; rep < 2; ++rep) {
            const int idx = threadIdx.x + (rep << 8);
            const int rr = idx >> 3, c8 = (idx & 7) << 3;
            bf16x8 av = {0, 0, 0, 0, 0, 0, 0, 0};
            if (rr < valid) {
                const int tk = perm[row0 + rr];
                av = *(const bf16x8*)(x1b + (size_t)tk * DD + k0 + c8);
            }
            *(bf16x8*)&As[rr][c8] = av;
            const bf16x8 bv = *(const bf16x8*)(Bbase + (size_t)rr * DD + k0 + c8);
            *(bf16x8*)&Bs[rr][c8] = bv;
        }
        __syncthreads();
#pragma unroll
        for (int ks = 0; ks < 2; ++ks) {
            const int kc = (ks << 5) + (lg << 3);
            const bf16x8 a  = *(const bf16x8*)&As[(wid << 4) + l15][kc];
            const bf16x8 f0 = *(const bf16x8*)&Bs[ 0 + l15][kc];
            const bf16x8 f1 = *(const bf16x8*)&Bs[16 + l15][kc];
            const bf16x8 f2 = *(const bf16x8*)&Bs[32 + l15][kc];
            const bf16x8 f3 = *(const bf16x8*)&Bs[48 + l15][kc];
            acc0 = __builtin_amdgcn_mfma_f32_16x16x32_bf16(a, f0, acc0, 0, 0, 0);
            acc1 = __builtin_amdgcn_mfma_f32_16x16x32_bf16(a, f1, acc1, 0, 0, 0);
            acc2 = __builtin_amdgcn_mfma_f32_16x16x32_bf16(a, f2, acc2, 0, 0, 0);
            acc3 = __builtin_amdgcn_mfma_f32_16x16x32_bf16(a, f3, acc3, 0, 0, 0);
        }
        __syncthreads();
    }
    const float* bias = b1 + e * FF + n0;
    const int mbase = (wid << 4) + (lg << 2);
#pragma unroll
    for (int nt = 0; nt < 4; ++nt) {
        const f32x4 ac = (nt == 0) ? acc0 : (nt == 1) ? acc1 : (nt == 2) ? acc2 : acc3;
        const int n = (nt << 4) + l15;
#pragma unroll
        for (int r2 = 0; r2 < 4; ++r2) {
            const int m = mbase + r2;
            if (m < valid) {
                float v = ac[r2] + bias[n];
                v = fmaxf(v, 0.f);
                hbuf[(size_t)(row0 + m) * FF + n0 + n] = f2bf(v);
            }
        }
    }
}

// ---------------------------------------------------------------------------
// MoE expert GEMM 2: res2[tk] = x1[tk] + gate[tk]*(h[slot] . w2t[e]^T + b2[e])
// ---------------------------------------------------------------------------
__global__ __launch_bounds__(256) void moe_gemm2_kernel(
    const unsigned short* __restrict__ hbuf, const unsigned short* __restrict__ w2t,
    const float* __restrict__ b2, const int* __restrict__ offs,
    const int* __restrict__ perm, const float* __restrict__ gate,
    const float* __restrict__ x1, float* __restrict__ res2)
{
    const int e = blockIdx.y >> 5, mt = blockIdx.y & 31;
    const int row0 = offs[e] + (mt << 6);
    const int rend = offs[e + 1];
    if (row0 >= rend) return;
    const int valid = (rend - row0 < 64) ? (rend - row0) : 64;
    const int n0 = blockIdx.x << 6;
    __shared__ unsigned short As[64][72];
    __shared__ unsigned short Bs[64][72];
    const int lane = threadIdx.x & 63, wid = threadIdx.x >> 6;
    const int l15 = lane & 15, lg = lane >> 4;
    f32x4 acc0 = {0.f, 0.f, 0.f, 0.f}, acc1 = acc0, acc2 = acc0, acc3 = acc0;
    const unsigned short* Bbase = w2t + (size_t)e * DD * FF + (size_t)n0 * FF;
    for (int k0 = 0; k0 < FF; k0 += 64) {
#pragma unroll
        for (int rep = 0; rep < 2; ++rep) {
            const int idx = threadIdx.x + (rep << 8);
            const int rr = idx >> 3, c8 = (idx & 7) << 3;
            bf16x8 av = {0, 0, 0, 0, 0, 0, 0, 0};
            if (rr < valid) av = *(const bf16x8*)(hbuf + (size_t)(row0 + rr) * FF + k0 + c8);
            *(bf16x8*)&As[rr][c8] = av;
            const bf16x8 bv = *(const bf16x8*)(Bbase + (size_t)rr * FF + k0 + c8);
            *(bf16x8*)&Bs[rr][c8] = bv;
        }
        __syncthreads();
#pragma unroll
        for (int ks = 0; ks < 2; ++ks) {
            const int kc = (ks << 5) + (lg << 3);
            const bf16x8 a  = *(const bf16x8*)&As[(wid << 4) + l15][kc];
            const bf16x8 f0 = *(const bf16x8*)&Bs[ 0 + l15][kc];
            const bf16x8 f1 = *(const bf16x8*)&Bs[16 + l15][kc];
            const bf16x8 f2 = *(const bf16x8*)&Bs[32 + l15][kc];
            const bf16x8 f3 = *(const bf16x8*)&Bs[48 + l15][kc];
            acc0 = __builtin_amdgcn_mfma_f32_16x16x32_bf16(a, f0, acc0, 0, 0, 0);
            acc1 = __builtin_amdgcn_mfma_f32_16x16x32_bf16(a, f1, acc1, 0, 0, 0);
            acc2 = __builtin_amdgcn_mfma_f32_16x16x32_bf16(a, f2, acc2, 0, 0, 0);
            acc3 = __builtin_amdgcn_mfma_f32_16x16x32_bf16(a, f3, acc3, 0, 0, 0);
        }
        __syncthreads();
    }
    const int mbase = (wid << 4) + (lg << 2);
#pragma unroll
    for (int nt = 0; nt < 4; ++nt) {
        const f32x4 ac = (nt == 0) ? acc0 : (nt == 1) ? acc1 : (nt == 2) ? acc2 : acc3;
        const int nl = (nt << 4) + l15;
#pragma unroll
        for (int r2 = 0; r2 < 4; ++r2) {
            const int m = mbase + r2;
            if (m < valid) {
                const int tk = perm[row0 + m];
                const float v = ac[r2] + b2[e * DD + n0 + nl];
                const size_t oi = (size_t)tk * DD + n0 + nl;
                res2[oi] = x1[oi] + gate[tk] * v;
            }
        }
    }
}

// ---------------------------------------------------------------------------
extern "C" void kernel_launch(void* const* d_in, const int* in_sizes, int n_in,
                              void* d_out, int out_size, void* d_ws, size_t ws_size,
                              hipStream_t stream)
{
    (void)in_sizes; (void)n_in; (void)out_size; (void)ws_size;
    const float* x   = (const float*)d_in[0];
    const float* wi  = (const float*)d_in[1];
    const float* bi  = (const float*)d_in[2];
    const float* wo  = (const float*)d_in[3];
    const float* bo  = (const float*)d_in[4];
    const float* g1  = (const float*)d_in[5];
    const float* be1 = (const float*)d_in[6];
    const float* g2  = (const float*)d_in[7];
    const float* be2 = (const float*)d_in[8];
    const float* wgr = (const float*)d_in[9];
    const float* bgr = (const float*)d_in[10];
    const float* wex = (const float*)d_in[11];
    const float* bex = (const float*)d_in[12];
    const float* w1  = (const float*)d_in[13];
    const float* b1  = (const float*)d_in[14];
    const float* w2  = (const float*)d_in[15];
    const float* b2  = (const float*)d_in[16];
    float* out = (float*)d_out;

    char* ws = (char*)d_ws;
    float* qkv            = (float*)(ws + 0);          // 25,165,824 B (reused below)
    unsigned short* hbuf  = (unsigned short*)(ws + 0); // 8 MB (aliases qkv, post-attn)
    float* res2           = (float*)(ws + 8388608);    // 8 MB (aliases qkv, post-attn)
    float* obuf           = (float*)(ws + 25165824);   // 8 MB
    float* res1           = (float*)(ws + 33554432);   // 8 MB
    float* x1             = (float*)(ws + 41943040);   // 8 MB
    unsigned short* x1b   = (unsigned short*)(ws + 50331648);  // 4 MB
    unsigned short* w1t   = (unsigned short*)(ws + 54525952);  // 32 MB
    unsigned short* w2t   = (unsigned short*)(ws + 88080384);  // 32 MB
    char* misc = ws + 121634816;
    int*   eid    = (int*)(misc);
    float* gate   = (float*)(misc + 8192);
    int*   perm   = (int*)(misc + 16384);
    int*   counts = (int*)(misc + 24576);
    int*   offs   = (int*)(misc + 24640);
    int*   cursor = (int*)(misc + 24704);

    // Aliased split-plane buffers (live only before their host region is written):
    unsigned short* xs_hi = (unsigned short*)(ws + 33554432);  // res1 region (dead until out-proj)
    unsigned short* xs_lo = (unsigned short*)(ws + 33554432 + 4194304);
    unsigned short* wi_hi = (unsigned short*)(ws + 54525952);  // w1t region (transposed later)
    unsigned short* wi_lo = (unsigned short*)(ws + 54525952 + 6291456);
    unsigned short* o_hi  = (unsigned short*)(ws + 41943040);  // x1 region (dead until LN1)
    unsigned short* o_lo  = (unsigned short*)(ws + 41943040 + 4194304);
    unsigned short* wo_hi = (unsigned short*)(ws + 88080384);  // w2t region (transposed later)
    unsigned short* wo_lo = (unsigned short*)(ws + 88080384 + 2097152);

    // --- split x and in_proj_w, then QKV = x @ wi^T + bi (split MFMA, fp32-exact-ish)
    split_bf16_kernel<<<dim3((TT * DD / 4 + 255) / 256), dim3(256), 0, stream>>>(x, xs_hi, xs_lo, TT * DD / 4);
    split_bf16_kernel<<<dim3((3 * DD * DD / 4 + 255) / 256), dim3(256), 0, stream>>>(wi, wi_hi, wi_lo, 3 * DD * DD / 4);
    gemm_split_kernel<<<dim3(3 * DD / 128, TT / 128), dim3(256), 0, stream>>>(
        xs_hi, xs_lo, wi_hi, wi_lo, bi, (const float*)nullptr, qkv, TT, 3 * DD, DD);

    // --- attention (fp32 flash)
    attn_kernel<<<dim3(SS / 64, 2 * NHD), dim3(256), 0, stream>>>(qkv, obuf);

    // --- split o and out_proj_w, then res1 = x + o @ wo^T + bo
    split_bf16_kernel<<<dim3((TT * DD / 4 + 255) / 256), dim3(256), 0, stream>>>(obuf, o_hi, o_lo, TT * DD / 4);
    split_bf16_kernel<<<dim3((DD * DD / 4 + 255) / 256), dim3(256), 0, stream>>>(wo, wo_hi, wo_lo, DD * DD / 4);
    gemm_split_kernel<<<dim3(DD / 128, TT / 128), dim3(256), 0, stream>>>(
        o_hi, o_lo, wo_hi, wo_lo, bo, x, res1, TT, DD, DD);

    // --- LN1 -> x1 (fp32) + x1b (bf16)   (overwrites o_hi/o_lo region: now dead)
    ln_kernel<<<dim3(TT), dim3(256), 0, stream>>>(res1, g1, be1, x1, x1b);

    // --- routing
    zero_counts_kernel<<<dim3(1), dim3(64), 0, stream>>>(counts);
    route_kernel<<<dim3(TT / 4), dim3(256), 0, stream>>>(x1, wgr, bgr, wex, bex, eid, gate, counts);
    offsets_kernel<<<dim3(1), dim3(64), 0, stream>>>(counts, offs, cursor);
    scatter_kernel<<<dim3(TT / 256), dim3(256), 0, stream>>>(eid, cursor, perm);

    // --- expert weights -> bf16 [N][K] (overwrites wi/wo split planes: now dead)
    transpose_bf16_kernel<<<dim3(FF / 32, DD / 32, NE), dim3(256), 0, stream>>>(w1, w1t, DD, FF);
    transpose_bf16_kernel<<<dim3(DD / 32, FF / 32, NE), dim3(256), 0, stream>>>(w2, w2t, FF, DD);

    // --- sparse expert FFN (bf16 MFMA)
    moe_gemm1_kernel<<<dim3(FF / 64, NE * 32), dim3(256), 0, stream>>>(x1b, w1t, b1, offs, perm, hbuf);
    moe_gemm2_kernel<<<dim3(DD / 64, NE * 32), dim3(256), 0, stream>>>(hbuf, w2t, b2, offs, perm, gate, x1, res2);

    // --- LN2 -> final output (fp32)
    ln_kernel<<<dim3(TT), dim3(256), 0, stream>>>(res2, g2, be2, out, (unsigned short*)nullptr);
}

// Round 3
// 365.376 us; speedup vs baseline: 1.5819x; 1.2051x over previous
//
#include <hip/hip_runtime.h>
#include <hip/hip_bf16.h>

// Problem constants (B=2, S=1024, D=1024, F=2048, H=16, hd=64, G=4, Epg=2, E=8)
#define TT 2048
#define DD 1024
#define FF 2048
#define SS 1024
#define NHD 16
#define HDD 64
#define NG 4
#define EPG 2
#define NE 8

typedef __attribute__((ext_vector_type(8))) short bf16x8;
typedef __attribute__((ext_vector_type(4))) float f32x4;
typedef __attribute__((ext_vector_type(4))) unsigned short ush4;

__device__ __forceinline__ unsigned short f2bf(float x) {
    unsigned int u = __float_as_uint(x);
    u = (u + 0x7fffu + ((u >> 16) & 1u)) >> 16;
    return (unsigned short)u;
}
__device__ __forceinline__ float bf2f(unsigned short h) {
    return __uint_as_float((unsigned int)h << 16);
}

__device__ __forceinline__ float wave_sum(float s) {
#pragma unroll
    for (int off = 32; off > 0; off >>= 1) s += __shfl_xor(s, off);
    return s;
}

// ---------------------------------------------------------------------------
// fp32 -> bf16 hi/lo split planes
// ---------------------------------------------------------------------------
__global__ __launch_bounds__(256) void split_bf16_kernel(
    const float* __restrict__ in, unsigned short* __restrict__ hi,
    unsigned short* __restrict__ lo, int n4)
{
    const int i = blockIdx.x * 256 + threadIdx.x;
    if (i >= n4) return;
    const float4 v = ((const float4*)in)[i];
    float vv[4] = {v.x, v.y, v.z, v.w};
    ush4 h, l;
#pragma unroll
    for (int j = 0; j < 4; ++j) {
        const unsigned short hb = f2bf(vv[j]);
        ((unsigned short*)&h)[j] = hb;
        ((unsigned short*)&l)[j] = f2bf(vv[j] - bf2f(hb));
    }
    ((ush4*)hi)[i] = h;
    ((ush4*)lo)[i] = l;
}

// ---------------------------------------------------------------------------
// Split-precision GEMM: C[M,N] = A[M,K] . B[N,K]^T + bias (+resid).
// A ~ Ah+Al, B ~ Bh+Bl (bf16 planes). 3-term MFMA: AhBh + AhBl + AlBh.
// 128x128 tile, BK=64, 4 waves, XOR-swizzled LDS.
// If Chi != null: write bf16 hi/lo split output (cols < qscale_n scaled by 1/8)
// instead of fp32 C.
// ---------------------------------------------------------------------------
__global__ __launch_bounds__(256, 2) void gemm_split_kernel(
    const unsigned short* __restrict__ Ah, const unsigned short* __restrict__ Al,
    const unsigned short* __restrict__ Bh, const unsigned short* __restrict__ Bl,
    const float* __restrict__ bias, const float* __restrict__ resid,
    float* __restrict__ C, unsigned short* __restrict__ Chi,
    unsigned short* __restrict__ Clo, int qscale_n, int M, int N, int K)
{
    __shared__ unsigned short sAh[128 * 64];
    __shared__ unsigned short sAl[128 * 64];
    __shared__ unsigned short sBh[128 * 64];
    __shared__ unsigned short sBl[128 * 64];
    const int tid = threadIdx.x;
    const int lane = tid & 63, wid = tid >> 6;
    const int l15 = lane & 15, lg = lane >> 4;
    const int wr = wid >> 1, wc = wid & 1;
    const int n0 = blockIdx.x << 7, m0 = blockIdx.y << 7;

    f32x4 acc[4][4];
#pragma unroll
    for (int mi = 0; mi < 4; ++mi)
#pragma unroll
        for (int ni = 0; ni < 4; ++ni) acc[mi][ni] = (f32x4){0.f, 0.f, 0.f, 0.f};

    for (int k0 = 0; k0 < K; k0 += 64) {
#pragma unroll
        for (int r = 0; r < 4; ++r) {
            const int s = tid + (r << 8);
            const int row = s >> 3, c = s & 7;
            const int phys = (s & ~7) | (c ^ (row & 7));
            const size_t ga = (size_t)(m0 + row) * K + k0 + (c << 3);
            const size_t gb = (size_t)(n0 + row) * K + k0 + (c << 3);
            *(bf16x8*)&sAh[phys << 3] = *(const bf16x8*)(Ah + ga);
            *(bf16x8*)&sAl[phys << 3] = *(const bf16x8*)(Al + ga);
            *(bf16x8*)&sBh[phys << 3] = *(const bf16x8*)(Bh + gb);
            *(bf16x8*)&sBl[phys << 3] = *(const bf16x8*)(Bl + gb);
        }
        __syncthreads();
#pragma unroll
        for (int ks = 0; ks < 2; ++ks) {
            bf16x8 ah[4], al[4], bh[4], bl[4];
            const int ac = (ks << 2) + lg;
#pragma unroll
            for (int i = 0; i < 4; ++i) {
                const int ar = (wr << 6) + (i << 4) + l15;
                const int pa = ((ar << 3) | (ac ^ (ar & 7))) << 3;
                ah[i] = *(const bf16x8*)&sAh[pa];
                al[i] = *(const bf16x8*)&sAl[pa];
                const int br = (wc << 6) + (i << 4) + l15;
                const int pb = ((br << 3) | (ac ^ (br & 7))) << 3;
                bh[i] = *(const bf16x8*)&sBh[pb];
                bl[i] = *(const bf16x8*)&sBl[pb];
            }
#pragma unroll
            for (int mi = 0; mi < 4; ++mi)
#pragma unroll
                for (int ni = 0; ni < 4; ++ni) {
                    acc[mi][ni] = __builtin_amdgcn_mfma_f32_16x16x32_bf16(ah[mi], bh[ni], acc[mi][ni], 0, 0, 0);
                    acc[mi][ni] = __builtin_amdgcn_mfma_f32_16x16x32_bf16(ah[mi], bl[ni], acc[mi][ni], 0, 0, 0);
                    acc[mi][ni] = __builtin_amdgcn_mfma_f32_16x16x32_bf16(al[mi], bh[ni], acc[mi][ni], 0, 0, 0);
                }
        }
        __syncthreads();
    }
#pragma unroll
    for (int mi = 0; mi < 4; ++mi)
#pragma unroll
        for (int ni = 0; ni < 4; ++ni)
#pragma unroll
            for (int r2 = 0; r2 < 4; ++r2) {
                const int m = m0 + (wr << 6) + (mi << 4) + (lg << 2) + r2;
                const int n = n0 + (wc << 6) + (ni << 4) + l15;
                float v = acc[mi][ni][r2] + bias[n];
                if (resid) v += resid[(size_t)m * N + n];
                const size_t idx = (size_t)m * N + n;
                if (Chi) {
                    if (n < qscale_n) v *= 0.125f;
                    const unsigned short hb = f2bf(v);
                    Chi[idx] = hb;
                    Clo[idx] = f2bf(v - bf2f(hb));
                } else {
                    C[idx] = v;
                }
            }
}

// ---------------------------------------------------------------------------
// V^T extraction: bf16 plane [t][3072] (V = cols 2048..3071 per head) ->
// [bh][64 d][1024 s] transposed plane. Called once for hi, once for lo.
// ---------------------------------------------------------------------------
__global__ __launch_bounds__(256) void vtrans_kernel(
    const unsigned short* __restrict__ src, unsigned short* __restrict__ dst)
{
    __shared__ unsigned short tile[64][65];
    const int bh = blockIdx.y, b = bh >> 4, h = bh & 15;
    const int s0 = blockIdx.x << 6;
    const int tid = threadIdx.x;
#pragma unroll
    for (int r = 0; r < 2; ++r) {
        const int sl = tid + (r << 8);
        const int rr = sl >> 3, c8 = (sl & 7) << 3;
        const bf16x8 v = *(const bf16x8*)(src + (size_t)(b * SS + s0 + rr) * 3072 + 2048 + h * HDD + c8);
#pragma unroll
        for (int j = 0; j < 8; ++j) tile[rr][c8 + j] = ((const unsigned short*)&v)[j];
    }
    __syncthreads();
#pragma unroll
    for (int r = 0; r < 2; ++r) {
        const int sl = tid + (r << 8);
        const int d = sl >> 3, s8 = (sl & 7) << 3;
        bf16x8 o;
#pragma unroll
        for (int j = 0; j < 8; ++j) ((unsigned short*)&o)[j] = tile[s8 + j][d];
        *(bf16x8*)(dst + (size_t)(bh * HDD + d) * SS + s0 + s8) = o;
    }
}

// ---------------------------------------------------------------------------
// Split-precision MFMA flash attention.
// grid (S/64, B*H), 256 threads = 4 waves, each wave owns 16 q-rows.
// Q pre-scaled by 1/8 (folded into QKV gemm epilogue). P round-trips through
// LDS (aliased onto dead K tile) to re-distribute C-layout -> A-layout.
// Writes split o hi/lo planes directly.
// ---------------------------------------------------------------------------
__global__ __launch_bounds__(256) void attn_mfma_kernel(
    const unsigned short* __restrict__ qh, const unsigned short* __restrict__ ql,
    const unsigned short* __restrict__ vth, const unsigned short* __restrict__ vtl,
    unsigned short* __restrict__ ohi, unsigned short* __restrict__ olo)
{
    __shared__ unsigned short sQh[4096], sQl[4096];
    __shared__ unsigned short sKh[4096], sKl[4096];   // aliased as P^T hi/lo after QK
    __shared__ unsigned short sVh[4096], sVl[4096];
    const int bh = blockIdx.y, b = bh >> 4, h = bh & 15;
    const int q0 = blockIdx.x << 6;
    const int tid = threadIdx.x, lane = tid & 63, w = tid >> 6;
    const int l15 = lane & 15, lg = lane >> 4;

    // stage Q tile (rows q0..q0+63), swizzled [row][slot^(row&7)]
#pragma unroll
    for (int r = 0; r < 2; ++r) {
        const int s = tid + (r << 8);
        const int row = s >> 3, c = s & 7;
        const int phys = ((row << 3) | (c ^ (row & 7))) << 3;
        const size_t g = (size_t)(b * SS + q0 + row) * 3072 + h * HDD + (c << 3);
        *(bf16x8*)&sQh[phys] = *(const bf16x8*)(qh + g);
        *(bf16x8*)&sQl[phys] = *(const bf16x8*)(ql + g);
    }

    f32x4 accO[4];
#pragma unroll
    for (int nt = 0; nt < 4; ++nt) accO[nt] = (f32x4){0.f, 0.f, 0.f, 0.f};
    float m_run[4], l_run[4];
#pragma unroll
    for (int r2 = 0; r2 < 4; ++r2) { m_run[r2] = -3.0e38f; l_run[r2] = 0.f; }

    for (int kv0 = 0; kv0 < SS; kv0 += 64) {
        // stage K tile + V^T tile
#pragma unroll
        for (int r = 0; r < 2; ++r) {
            const int s = tid + (r << 8);
            const int row = s >> 3, c = s & 7;
            const int phys = ((row << 3) | (c ^ (row & 7))) << 3;
            const size_t gk = (size_t)(b * SS + kv0 + row) * 3072 + DD + h * HDD + (c << 3);
            *(bf16x8*)&sKh[phys] = *(const bf16x8*)(qh + gk);
            *(bf16x8*)&sKl[phys] = *(const bf16x8*)(ql + gk);
            const size_t gv = (size_t)(bh * HDD + row) * SS + kv0 + (c << 3);
            *(bf16x8*)&sVh[phys] = *(const bf16x8*)(vth + gv);
            *(bf16x8*)&sVl[phys] = *(const bf16x8*)(vtl + gv);
        }
        __syncthreads();

        // QK^T: S[q=w*16+lg*4+r2][kv=i*16+l15]
        f32x4 sacc[4];
#pragma unroll
        for (int i = 0; i < 4; ++i) sacc[i] = (f32x4){0.f, 0.f, 0.f, 0.f};
#pragma unroll
        for (int ks = 0; ks < 2; ++ks) {
            const int ac = (ks << 2) + lg;
            const int ar = (w << 4) + l15;
            const int pa = ((ar << 3) | (ac ^ (ar & 7))) << 3;
            const bf16x8 ah = *(const bf16x8*)&sQh[pa];
            const bf16x8 al = *(const bf16x8*)&sQl[pa];
#pragma unroll
            for (int i = 0; i < 4; ++i) {
                const int br = (i << 4) + l15;
                const int pb = ((br << 3) | (ac ^ (br & 7))) << 3;
                const bf16x8 kbh = *(const bf16x8*)&sKh[pb];
                const bf16x8 kbl = *(const bf16x8*)&sKl[pb];
                sacc[i] = __builtin_amdgcn_mfma_f32_16x16x32_bf16(ah, kbh, sacc[i], 0, 0, 0);
                sacc[i] = __builtin_amdgcn_mfma_f32_16x16x32_bf16(ah, kbl, sacc[i], 0, 0, 0);
                sacc[i] = __builtin_amdgcn_mfma_f32_16x16x32_bf16(al, kbh, sacc[i], 0, 0, 0);
            }
        }
        __syncthreads();   // all waves done reading K before P overwrites it

        // online softmax per q-row (reduce across the 16 lanes of l15)
#pragma unroll
        for (int r2 = 0; r2 < 4; ++r2) {
            float mx = fmaxf(fmaxf(sacc[0][r2], sacc[1][r2]), fmaxf(sacc[2][r2], sacc[3][r2]));
#pragma unroll
            for (int off = 1; off < 16; off <<= 1) mx = fmaxf(mx, __shfl_xor(mx, off));
            const float mn = fmaxf(m_run[r2], mx);
            const float corr = __expf(m_run[r2] - mn);
            m_run[r2] = mn;
            float ls = 0.f;
#pragma unroll
            for (int nt = 0; nt < 4; ++nt) {
                const float p = __expf(sacc[nt][r2] - mn);
                sacc[nt][r2] = p;
                ls += p;
            }
#pragma unroll
            for (int off = 1; off < 16; off <<= 1) ls += __shfl_xor(ls, off);
            l_run[r2] = l_run[r2] * corr + ls;
#pragma unroll
            for (int nt = 0; nt < 4; ++nt) accO[nt][r2] *= corr;
        }

        // write P^T[kv][q] hi/lo into the dead K LDS (slot-swizzled)
#pragma unroll
        for (int nt = 0; nt < 4; ++nt) {
            ush4 hp, lp;
#pragma unroll
            for (int r2 = 0; r2 < 4; ++r2) {
                const float p = sacc[nt][r2];
                const unsigned short hb = f2bf(p);
                hp[r2] = hb;
                lp[r2] = f2bf(p - bf2f(hb));
            }
            const int kv = (nt << 4) + l15;
            const int qq = (w << 4) + (lg << 2);
            const int idx = (kv << 6) + (((qq >> 3) ^ (kv & 7)) << 3) + (qq & 7);
            *(ush4*)&sKh[idx] = hp;
            *(ush4*)&sKl[idx] = lp;
        }
        __syncthreads();

        // PV: O[q=lg*4+r2][d=nt*16+l15] += P[q][kv] * V[kv][d]
#pragma unroll
        for (int ks = 0; ks < 2; ++ks) {
            bf16x8 pah, pal;
            const int qq = (w << 4) + l15;
#pragma unroll
            for (int j = 0; j < 8; ++j) {
                const int kv = (ks << 5) + (lg << 3) + j;
                const int idx = (kv << 6) + (((qq >> 3) ^ (kv & 7)) << 3) + (qq & 7);
                ((unsigned short*)&pah)[j] = sKh[idx];
                ((unsigned short*)&pal)[j] = sKl[idx];
            }
            const int ac = (ks << 2) + lg;
#pragma unroll
            for (int nt = 0; nt < 4; ++nt) {
                const int dr = (nt << 4) + l15;
                const int pv = ((dr << 3) | (ac ^ (dr & 7))) << 3;
                const bf16x8 vbh = *(const bf16x8*)&sVh[pv];
                const bf16x8 vbl = *(const bf16x8*)&sVl[pv];
                accO[nt] = __builtin_amdgcn_mfma_f32_16x16x32_bf16(pah, vbh, accO[nt], 0, 0, 0);
                accO[nt] = __builtin_amdgcn_mfma_f32_16x16x32_bf16(pah, vbl, accO[nt], 0, 0, 0);
                accO[nt] = __builtin_amdgcn_mfma_f32_16x16x32_bf16(pal, vbh, accO[nt], 0, 0, 0);
            }
        }
        __syncthreads();   // P/V reads done before next tile's staging
    }

    // epilogue: normalize and write split o planes
    float inv[4];
#pragma unroll
    for (int r2 = 0; r2 < 4; ++r2) inv[r2] = 1.0f / l_run[r2];
#pragma unroll
    for (int nt = 0; nt < 4; ++nt)
#pragma unroll
        for (int r2 = 0; r2 < 4; ++r2) {
            const int qq = q0 + (w << 4) + (lg << 2) + r2;
            const int dd = (nt << 4) + l15;
            const float v = accO[nt][r2] * inv[r2];
            const unsigned short hb = f2bf(v);
            const size_t oi = (size_t)(b * SS + qq) * DD + h * HDD + dd;
            ohi[oi] = hb;
            olo[oi] = f2bf(v - bf2f(hb));
        }
}

// ---------------------------------------------------------------------------
// LayerNorm per row; writes fp32 (+ optional bf16 copy).
// ---------------------------------------------------------------------------
__global__ __launch_bounds__(256) void ln_kernel(
    const float* __restrict__ in, const float* __restrict__ gamma,
    const float* __restrict__ beta, float* __restrict__ outf,
    unsigned short* __restrict__ outb)
{
    const int t = blockIdx.x;
    const int tid = threadIdx.x;
    __shared__ float red[8];
    const float4 v = ((const float4*)(in + (size_t)t * DD))[tid];
    float s = v.x + v.y + v.z + v.w;
    s = wave_sum(s);
    const int wid = tid >> 6, lane = tid & 63;
    if (lane == 0) red[wid] = s;
    __syncthreads();
    const float mu = (red[0] + red[1] + red[2] + red[3]) * (1.0f / DD);
    const float d0 = v.x - mu, d1 = v.y - mu, d2 = v.z - mu, d3 = v.w - mu;
    float q = d0 * d0 + d1 * d1 + d2 * d2 + d3 * d3;
    q = wave_sum(q);
    if (lane == 0) red[4 + wid] = q;
    __syncthreads();
    const float var = (red[4] + red[5] + red[6] + red[7]) * (1.0f / DD);
    const float rstd = 1.0f / sqrtf(var + 1e-5f);
    const float4 g4 = ((const float4*)gamma)[tid];
    const float4 b4 = ((const float4*)beta)[tid];
    const float o0 = d0 * rstd * g4.x + b4.x;
    const float o1 = d1 * rstd * g4.y + b4.y;
    const float o2 = d2 * rstd * g4.z + b4.z;
    const float o3 = d3 * rstd * g4.w + b4.w;
    float4 ov = {o0, o1, o2, o3};
    ((float4*)(outf + (size_t)t * DD))[tid] = ov;
    if (outb) {
        ush4 wv = { f2bf(o0), f2bf(o1), f2bf(o2), f2bf(o3) };
        *(ush4*)(outb + (size_t)t * DD + (tid << 2)) = wv;
    }
}

// ---------------------------------------------------------------------------
// Hierarchical top-1 routing. One wave per token (fp32, exact-order reductions).
// ---------------------------------------------------------------------------
__global__ __launch_bounds__(256) void route_kernel(
    const float* __restrict__ x1, const float* __restrict__ wg,
    const float* __restrict__ bg, const float* __restrict__ we,
    const float* __restrict__ be, int* __restrict__ eid,
    float* __restrict__ gate, int* __restrict__ counts)
{
    const int lane = threadIdx.x & 63;
    const int t = (blockIdx.x << 2) + (threadIdx.x >> 6);
    const float* row = x1 + (size_t)t * DD;
    float zg[NG] = {};
    float ze[NG][EPG] = {};
#pragma unroll
    for (int jj = 0; jj < 16; ++jj) {
        const int c = (lane << 4) + jj;
        const float xv = row[c];
#pragma unroll
        for (int g = 0; g < NG; ++g) {
            zg[g] = fmaf(xv, wg[c * NG + g], zg[g]);
#pragma unroll
            for (int e2 = 0; e2 < EPG; ++e2)
                ze[g][e2] = fmaf(xv, we[(g * DD + c) * EPG + e2], ze[g][e2]);
        }
    }
#pragma unroll
    for (int off = 1; off < 64; off <<= 1) {
#pragma unroll
        for (int g = 0; g < NG; ++g) {
            zg[g] += __shfl_xor(zg[g], off);
#pragma unroll
            for (int e2 = 0; e2 < EPG; ++e2) ze[g][e2] += __shfl_xor(ze[g][e2], off);
        }
    }
    if (lane == 0) {
        float z[NG];
#pragma unroll
        for (int g = 0; g < NG; ++g) z[g] = zg[g] + bg[g];
        int gi = 0; float zb = z[0];
#pragma unroll
        for (int g = 1; g < NG; ++g) if (z[g] > zb) { zb = z[g]; gi = g; }
        float se = 0.f;
#pragma unroll
        for (int g = 0; g < NG; ++g) se += __expf(z[g] - zb);
        const float gprob = 1.0f / se;
        float e0 = 0.f, e1 = 0.f;
#pragma unroll
        for (int g = 0; g < NG; ++g) {
            if (g == gi) { e0 = ze[g][0] + be[g * EPG + 0]; e1 = ze[g][1] + be[g * EPG + 1]; }
        }
        const int ei = (e1 > e0) ? 1 : 0;
        const float ehi = ei ? e1 : e0, elo = ei ? e0 : e1;
        const float eprob = 1.0f / (1.0f + __expf(elo - ehi));
        eid[t] = gi * EPG + ei;
        gate[t] = gprob * eprob;
        atomicAdd(&counts[gi * EPG + ei], 1);
    }
}

__global__ void zero_counts_kernel(int* __restrict__ counts) {
    if (threadIdx.x < NE) counts[threadIdx.x] = 0;
}

__global__ void offsets_kernel(const int* __restrict__ counts, int* __restrict__ offs,
                               int* __restrict__ cursor) {
    if (threadIdx.x == 0) {
        int run = 0;
        for (int e = 0; e < NE; ++e) { offs[e] = run; cursor[e] = run; run += counts[e]; }
        offs[NE] = run;
    }
}

__global__ __launch_bounds__(256) void scatter_kernel(const int* __restrict__ eid,
                                                      int* __restrict__ cursor,
                                                      int* __restrict__ perm) {
    const int t = blockIdx.x * 256 + threadIdx.x;
    const int slot = atomicAdd(&cursor[eid[t]], 1);
    perm[slot] = t;
}

// ---------------------------------------------------------------------------
// fp32 [batch][R][C] -> bf16 [batch][C][R] (LDS-tiled transpose + convert)
// ---------------------------------------------------------------------------
__global__ __launch_bounds__(256) void transpose_bf16_kernel(
    const float* __restrict__ in, unsigned short* __restrict__ out, int R, int C)
{
    __shared__ float tile[32][33];
    const int c0 = blockIdx.x << 5, r0 = blockIdx.y << 5;
    const size_t bo = (size_t)blockIdx.z * R * C;
    const int tc = threadIdx.x & 31, tr8 = threadIdx.x >> 5;
#pragma unroll
    for (int p = 0; p < 4; ++p) {
        const int rr = tr8 + (p << 3);
        tile[rr][tc] = in[bo + (size_t)(r0 + rr) * C + c0 + tc];
    }
    __syncthreads();
#pragma unroll
    for (int p = 0; p < 4; ++p) {
        const int rr = tr8 + (p << 3);
        out[bo + (size_t)(c0 + rr) * R + r0 + tc] = f2bf(tile[tc][rr]);
    }
}

// ---------------------------------------------------------------------------
// MoE expert GEMM 1: h[slot][F] = relu(x1b[perm[slot]] . w1t[e]^T + b1[e])
// ---------------------------------------------------------------------------
__global__ __launch_bounds__(256) void moe_gemm1_kernel(
    const unsigned short* __restrict__ x1b, const unsigned short* __restrict__ w1t,
    const float* __restrict__ b1, const int* __restrict__ offs,
    const int* __restrict__ perm, unsigned short* __restrict__ hbuf)
{
    const int e = blockIdx.y >> 5, mt = blockIdx.y & 31;
    const int row0 = offs[e] + (mt << 6);
    const int rend = offs[e + 1];
    if (row0 >= rend) return;
    const int valid = (rend - row0 < 64) ? (rend - row0) : 64;
    const int n0 = blockIdx.x << 6;
    __shared__ unsigned short As[64][72];
    __shared__ unsigned short Bs[64][72];
    const int lane = threadIdx.x & 63, wid = threadIdx.x >> 6;
    const int l15 = lane & 15, lg = lane >> 4;
    f32x4 acc0 = {0.f, 0.f, 0.f, 0.f}, acc1 = acc0, acc2 = acc0, acc3 = acc0;
    const unsigned short* Bbase = w1t + (size_t)e * FF * DD + (size_t)n0 * DD;
    for (int k0 = 0; k0 < DD; k0 += 64) {
#pragma unroll
        for (int rep = 0; rep < 2; ++rep) {
            const int idx = threadIdx.x + (rep << 8);
            const int rr = idx >> 3, c8 = (idx & 7) << 3;
            bf16x8 av = {0, 0, 0, 0, 0, 0, 0, 0};
            if (rr < valid) {
                const int tk = perm[row0 + rr];
                av = *(const bf16x8*)(x1b + (size_t)tk * DD + k0 + c8);
            }
            *(bf16x8*)&As[rr][c8] = av;
            const bf16x8 bv = *(const bf16x8*)(Bbase + (size_t)rr * DD + k0 + c8);
            *(bf16x8*)&Bs[rr][c8] = bv;
        }
        __syncthreads();
#pragma unroll
        for (int ks = 0; ks < 2; ++ks) {
            const int kc = (ks << 5) + (lg << 3);
            const bf16x8 a  = *(const bf16x8*)&As[(wid << 4) + l15][kc];
            const bf16x8 f0 = *(const bf16x8*)&Bs[ 0 + l15][kc];
            const bf16x8 f1 = *(const bf16x8*)&Bs[16 + l15][kc];
            const bf16x8 f2 = *(const bf16x8*)&Bs[32 + l15][kc];
            const bf16x8 f3 = *(const bf16x8*)&Bs[48 + l15][kc];
            acc0 = __builtin_amdgcn_mfma_f32_16x16x32_bf16(a, f0, acc0, 0, 0, 0);
            acc1 = __builtin_amdgcn_mfma_f32_16x16x32_bf16(a, f1, acc1, 0, 0, 0);
            acc2 = __builtin_amdgcn_mfma_f32_16x16x32_bf16(a, f2, acc2, 0, 0, 0);
            acc3 = __builtin_amdgcn_mfma_f32_16x16x32_bf16(a, f3, acc3, 0, 0, 0);
        }
        __syncthreads();
    }
    const float* bias = b1 + e * FF + n0;
    const int mbase = (wid << 4) + (lg << 2);
#pragma unroll
    for (int nt = 0; nt < 4; ++nt) {
        const f32x4 ac = (nt == 0) ? acc0 : (nt == 1) ? acc1 : (nt == 2) ? acc2 : acc3;
        const int n = (nt << 4) + l15;
#pragma unroll
        for (int r2 = 0; r2 < 4; ++r2) {
            const int m = mbase + r2;
            if (m < valid) {
                float v = ac[r2] + bias[n];
                v = fmaxf(v, 0.f);
                hbuf[(size_t)(row0 + m) * FF + n0 + n] = f2bf(v);
            }
        }
    }
}

// ---------------------------------------------------------------------------
// MoE expert GEMM 2: res2[tk] = x1[tk] + gate[tk]*(h[slot] . w2t[e]^T + b2[e])
// ---------------------------------------------------------------------------
__global__ __launch_bounds__(256) void moe_gemm2_kernel(
    const unsigned short* __restrict__ hbuf, const unsigned short* __restrict__ w2t,
    const float* __restrict__ b2, const int* __restrict__ offs,
    const int* __restrict__ perm, const float* __restrict__ gate,
    const float* __restrict__ x1, float* __restrict__ res2)
{
    const int e = blockIdx.y >> 5, mt = blockIdx.y & 31;
    const int row0 = offs[e] + (mt << 6);
    const int rend = offs[e + 1];
    if (row0 >= rend) return;
    const int valid = (rend - row0 < 64) ? (rend - row0) : 64;
    const int n0 = blockIdx.x << 6;
    __shared__ unsigned short As[64][72];
    __shared__ unsigned short Bs[64][72];
    const int lane = threadIdx.x & 63, wid = threadIdx.x >> 6;
    const int l15 = lane & 15, lg = lane >> 4;
    f32x4 acc0 = {0.f, 0.f, 0.f, 0.f}, acc1 = acc0, acc2 = acc0, acc3 = acc0;
    const unsigned short* Bbase = w2t + (size_t)e * DD * FF + (size_t)n0 * FF;
    for (int k0 = 0; k0 < FF; k0 += 64) {
#pragma unroll
        for (int rep = 0; rep < 2; ++rep) {
            const int idx = threadIdx.x + (rep << 8);
            const int rr = idx >> 3, c8 = (idx & 7) << 3;
            bf16x8 av = {0, 0, 0, 0, 0, 0, 0, 0};
            if (rr < valid) av = *(const bf16x8*)(hbuf + (size_t)(row0 + rr) * FF + k0 + c8);
            *(bf16x8*)&As[rr][c8] = av;
            const bf16x8 bv = *(const bf16x8*)(Bbase + (size_t)rr * FF + k0 + c8);
            *(bf16x8*)&Bs[rr][c8] = bv;
        }
        __syncthreads();
#pragma unroll
        for (int ks = 0; ks < 2; ++ks) {
            const int kc = (ks << 5) + (lg << 3);
            const bf16x8 a  = *(const bf16x8*)&As[(wid << 4) + l15][kc];
            const bf16x8 f0 = *(const bf16x8*)&Bs[ 0 + l15][kc];
            const bf16x8 f1 = *(const bf16x8*)&Bs[16 + l15][kc];
            const bf16x8 f2 = *(const bf16x8*)&Bs[32 + l15][kc];
            const bf16x8 f3 = *(const bf16x8*)&Bs[48 + l15][kc];
            acc0 = __builtin_amdgcn_mfma_f32_16x16x32_bf16(a, f0, acc0, 0, 0, 0);
            acc1 = __builtin_amdgcn_mfma_f32_16x16x32_bf16(a, f1, acc1, 0, 0, 0);
            acc2 = __builtin_amdgcn_mfma_f32_16x16x32_bf16(a, f2, acc2, 0, 0, 0);
            acc3 = __builtin_amdgcn_mfma_f32_16x16x32_bf16(a, f3, acc3, 0, 0, 0);
        }
        __syncthreads();
    }
    const int mbase = (wid << 4) + (lg << 2);
#pragma unroll
    for (int nt = 0; nt < 4; ++nt) {
        const f32x4 ac = (nt == 0) ? acc0 : (nt == 1) ? acc1 : (nt == 2) ? acc2 : acc3;
        const int nl = (nt << 4) + l15;
#pragma unroll
        for (int r2 = 0; r2 < 4; ++r2) {
            const int m = mbase + r2;
            if (m < valid) {
                const int tk = perm[row0 + m];
                const float v = ac[r2] + b2[e * DD + n0 + nl];
                const size_t oi = (size_t)tk * DD + n0 + nl;
                res2[oi] = x1[oi] + gate[tk] * v;
            }
        }
    }
}

// ---------------------------------------------------------------------------
extern "C" void kernel_launch(void* const* d_in, const int* in_sizes, int n_in,
                              void* d_out, int out_size, void* d_ws, size_t ws_size,
                              hipStream_t stream)
{
    (void)in_sizes; (void)n_in; (void)out_size; (void)ws_size;
    const float* x   = (const float*)d_in[0];
    const float* wi  = (const float*)d_in[1];
    const float* bi  = (const float*)d_in[2];
    const float* wo  = (const float*)d_in[3];
    const float* bo  = (const float*)d_in[4];
    const float* g1  = (const float*)d_in[5];
    const float* be1 = (const float*)d_in[6];
    const float* g2  = (const float*)d_in[7];
    const float* be2 = (const float*)d_in[8];
    const float* wgr = (const float*)d_in[9];
    const float* bgr = (const float*)d_in[10];
    const float* wex = (const float*)d_in[11];
    const float* bex = (const float*)d_in[12];
    const float* w1  = (const float*)d_in[13];
    const float* b1  = (const float*)d_in[14];
    const float* w2  = (const float*)d_in[15];
    const float* b2  = (const float*)d_in[16];
    float* out = (float*)d_out;

    char* ws = (char*)d_ws;
    // Workspace map (regions reused across phases; total ~121.7 MB):
    unsigned short* qkvh  = (unsigned short*)(ws + 0);         // 12 MB [t][3072]
    unsigned short* qkvl  = (unsigned short*)(ws + 12582912);  // 12 MB
    unsigned short* hbuf  = (unsigned short*)(ws + 0);         // 8 MB (post-attn, aliases qkvh)
    float* res2           = (float*)(ws + 8388608);            // 8 MB (post-attn)
    unsigned short* vth   = (unsigned short*)(ws + 25165824);  // 4 MB [bh][64][1024]
    unsigned short* vtl   = (unsigned short*)(ws + 29360128);  // 4 MB
    float* res1           = (float*)(ws + 33554432);           // 8 MB
    float* x1             = (float*)(ws + 41943040);           // 8 MB
    unsigned short* x1b   = (unsigned short*)(ws + 50331648);  // 4 MB
    unsigned short* w1t   = (unsigned short*)(ws + 54525952);  // 32 MB
    unsigned short* w2t   = (unsigned short*)(ws + 88080384);  // 32 MB
    char* misc = ws + 121634816;
    int*   eid    = (int*)(misc);
    float* gate   = (float*)(misc + 8192);
    int*   perm   = (int*)(misc + 16384);
    int*   counts = (int*)(misc + 24576);
    int*   offs   = (int*)(misc + 24640);
    int*   cursor = (int*)(misc + 24704);

    // Aliased split-plane buffers (dead before their host region is written):
    unsigned short* xs_hi = (unsigned short*)(ws + 33554432);            // res1 region
    unsigned short* xs_lo = (unsigned short*)(ws + 33554432 + 4194304);
    unsigned short* wi_hi = (unsigned short*)(ws + 54525952);            // w1t region
    unsigned short* wi_lo = (unsigned short*)(ws + 54525952 + 6291456);
    unsigned short* o_hi  = (unsigned short*)(ws + 41943040);            // x1 region
    unsigned short* o_lo  = (unsigned short*)(ws + 41943040 + 4194304);
    unsigned short* wo_hi = (unsigned short*)(ws + 88080384);            // w2t region
    unsigned short* wo_lo = (unsigned short*)(ws + 88080384 + 2097152);

    // --- split x and in_proj_w; QKV = x @ wi^T + bi -> split planes, Q pre-scaled 1/8
    split_bf16_kernel<<<dim3((TT * DD / 4 + 255) / 256), dim3(256), 0, stream>>>(x, xs_hi, xs_lo, TT * DD / 4);
    split_bf16_kernel<<<dim3((3 * DD * DD / 4 + 255) / 256), dim3(256), 0, stream>>>(wi, wi_hi, wi_lo, 3 * DD * DD / 4);
    gemm_split_kernel<<<dim3(3 * DD / 128, TT / 128), dim3(256), 0, stream>>>(
        xs_hi, xs_lo, wi_hi, wi_lo, bi, (const float*)nullptr,
        (float*)nullptr, qkvh, qkvl, DD, TT, 3 * DD, DD);

    // --- V^T planes for the PV MFMA B-operand
    vtrans_kernel<<<dim3(SS / 64, 2 * NHD), dim3(256), 0, stream>>>(qkvh, vth);
    vtrans_kernel<<<dim3(SS / 64, 2 * NHD), dim3(256), 0, stream>>>(qkvl, vtl);

    // --- split-precision MFMA flash attention -> o hi/lo planes
    attn_mfma_kernel<<<dim3(SS / 64, 2 * NHD), dim3(256), 0, stream>>>(
        qkvh, qkvl, vth, vtl, o_hi, o_lo);

    // --- split out_proj_w; res1 = x + o @ wo^T + bo (fp32 out)
    split_bf16_kernel<<<dim3((DD * DD / 4 + 255) / 256), dim3(256), 0, stream>>>(wo, wo_hi, wo_lo, DD * DD / 4);
    gemm_split_kernel<<<dim3(DD / 128, TT / 128), dim3(256), 0, stream>>>(
        o_hi, o_lo, wo_hi, wo_lo, bo, x,
        res1, (unsigned short*)nullptr, (unsigned short*)nullptr, 0, TT, DD, DD);

    // --- LN1 -> x1 (fp32) + x1b (bf16)   (overwrites o_hi/o_lo: now dead)
    ln_kernel<<<dim3(TT), dim3(256), 0, stream>>>(res1, g1, be1, x1, x1b);

    // --- routing
    zero_counts_kernel<<<dim3(1), dim3(64), 0, stream>>>(counts);
    route_kernel<<<dim3(TT / 4), dim3(256), 0, stream>>>(x1, wgr, bgr, wex, bex, eid, gate, counts);
    offsets_kernel<<<dim3(1), dim3(64), 0, stream>>>(counts, offs, cursor);
    scatter_kernel<<<dim3(TT / 256), dim3(256), 0, stream>>>(eid, cursor, perm);

    // --- expert weights -> bf16 [N][K] (overwrites wi/wo split planes: now dead)
    transpose_bf16_kernel<<<dim3(FF / 32, DD / 32, NE), dim3(256), 0, stream>>>(w1, w1t, DD, FF);
    transpose_bf16_kernel<<<dim3(DD / 32, FF / 32, NE), dim3(256), 0, stream>>>(w2, w2t, FF, DD);

    // --- sparse expert FFN (bf16 MFMA)
    moe_gemm1_kernel<<<dim3(FF / 64, NE * 32), dim3(256), 0, stream>>>(x1b, w1t, b1, offs, perm, hbuf);
    moe_gemm2_kernel<<<dim3(DD / 64, NE * 32), dim3(256), 0, stream>>>(hbuf, w2t, b2, offs, perm, gate, x1, res2);

    // --- LN2 -> final output (fp32)
    ln_kernel<<<dim3(TT), dim3(256), 0, stream>>>(res2, g2, be2, out, (unsigned short*)nullptr);
}